// Round 2
// baseline (256.012 us; speedup 1.0000x reference)
//
#include <hip/hip_runtime.h>

#define B_ 4
#define C_ 512
#define H_ 64
#define W_ 208
#define HID_ 512
#define NREG_ 4
#define DS_ 16

// ws layout: delta [B*NREG*C] fp32 @0 (32KB) | tmp [B*NREG*HID] fp32 @32KB | swl [B*W] int @64KB

// Blocks 0..31: partial tmp[b,r,d] = sum_{h in chunk} tf[r,b,h]*Wv[r,h,d]  (atomicAdd)
// Blocks 32..35: parallel stable counting sort of column labels for b = blk-32
__global__ __launch_bounds__(256) void prep1_kernel(
    const float* __restrict__ tf, const float* __restrict__ Wv,
    const int* __restrict__ mask, float* __restrict__ tmp, int* __restrict__ swl) {
  int blk = blockIdx.x, tid = threadIdx.x;
  if (blk < 32) {
    int r = blk >> 3, h0 = (blk & 7) * 64;
    __shared__ float tf_s[B_][64];
    {
      int b = tid >> 6, hh = tid & 63;
      tf_s[b][hh] = tf[(r * B_ + b) * HID_ + h0 + hh];
    }
    __syncthreads();
    float acc[B_][2] = {};
    for (int hh = 0; hh < 64; ++hh) {
      const float* row = Wv + (size_t)(r * HID_ + h0 + hh) * HID_;
      float w1 = row[tid], w2 = row[tid + 256];
#pragma unroll
      for (int b = 0; b < B_; ++b) {
        float t = tf_s[b][hh];
        acc[b][0] += t * w1;
        acc[b][1] += t * w2;
      }
    }
#pragma unroll
    for (int b = 0; b < B_; ++b) {
      atomicAdd(&tmp[(b * NREG_ + r) * HID_ + tid], acc[b][0]);
      atomicAdd(&tmp[(b * NREG_ + r) * HID_ + tid + 256], acc[b][1]);
    }
  } else {
    int b = blk - 32;
    const size_t mb = (size_t)b * (H_ * DS_) * (W_ * DS_);
    int w = tid;
    int l = (w < W_) ? (mask[mb + (size_t)w * DS_] - 1) : -1;
    int wave = tid >> 6, lane = tid & 63;
    unsigned long long bal[NREG_];
    __shared__ int wcnt[4][NREG_];
#pragma unroll
    for (int r = 0; r < NREG_; ++r) bal[r] = __ballot(l == r);
    if (lane < NREG_) wcnt[wave][lane] = __popcll(bal[lane]);
    __syncthreads();
    if (w < W_) {
      int pos = 0;
#pragma unroll
      for (int q = 0; q < NREG_; ++q) {
        int tot = wcnt[0][q] + wcnt[1][q] + wcnt[2][q] + wcnt[3][q];
        if (q < l) pos += tot;
      }
#pragma unroll
      for (int v = 0; v < 4; ++v)
        if (v < wave) pos += wcnt[v][l];
      pos += __popcll(bal[l] & ((1ull << lane) - 1ull));
      swl[b * W_ + pos] = w | (l << 16);
    }
  }
}

// delta[b,r,c] += sum_{d in chunk} tmp[b,r,d]*Wo[r,d,c]  (atomicAdd)
__global__ __launch_bounds__(256) void prep2_kernel(
    const float* __restrict__ tmp, const float* __restrict__ Wo,
    float* __restrict__ delta) {
  int blk = blockIdx.x, tid = threadIdx.x;
  int r = blk >> 3, d0 = (blk & 7) * 64;
  __shared__ float tmp_s[B_][64];
  {
    int b = tid >> 6, dd = tid & 63;
    tmp_s[b][dd] = tmp[(b * NREG_ + r) * HID_ + d0 + dd];
  }
  __syncthreads();
  float acc[B_][2] = {};
  for (int dd = 0; dd < 64; ++dd) {
    const float* row = Wo + (size_t)(r * HID_ + d0 + dd) * C_;
    float w1 = row[tid], w2 = row[tid + 256];
#pragma unroll
    for (int b = 0; b < B_; ++b) {
      float t = tmp_s[b][dd];
      acc[b][0] += t * w1;
      acc[b][1] += t * w2;
    }
  }
#pragma unroll
  for (int b = 0; b < B_; ++b) {
    atomicAdd(&delta[(b * NREG_ + b ? b * NREG_ * 0 : 0) + (b * NREG_ + r) * C_ - (b * NREG_ + r) * C_ + (b * NREG_ + r) * C_ + tid], acc[b][0]);
    atomicAdd(&delta[(b * NREG_ + r) * C_ + tid + 256], acc[b][1]);
  }
}

// Each block: 32 contiguous (b,c,h)-rows (constant b,c). Stage rows in LDS
// (float4 vectorized), gather-permute columns via LDS, add delta, store float4.
#define ROWS_ 32
#define RCH_ (W_ / 4)              // 52 float4 chunks per row
#define CHUNKS_ (ROWS_ * RCH_)     // 1664 per block
__global__ __launch_bounds__(256) void apply_kernel(
    const float* __restrict__ img, const float* __restrict__ delta,
    const int* __restrict__ swl, float* __restrict__ out) {
  int r0 = blockIdx.x * ROWS_;
  int b = r0 >> 15;                // / (C_*H_)
  int c = (r0 >> 6) & (C_ - 1);    // / H_ mod C_
  int tid = threadIdx.x;
  __shared__ float tile[ROWS_ * W_];
  __shared__ int swl_s[W_];
  __shared__ float dsel_s[NREG_];
  const float4* src = (const float4*)(img + (size_t)r0 * W_);
  float4* tile4 = (float4*)tile;
  for (int i = tid; i < CHUNKS_; i += 256) tile4[i] = src[i];
  if (tid < W_) swl_s[tid] = swl[b * W_ + tid];
  if (tid < NREG_) dsel_s[tid] = delta[(b * NREG_ + tid) * C_ + c];
  __syncthreads();
  float d0 = dsel_s[0], d1 = dsel_s[1], d2 = dsel_s[2], d3 = dsel_s[3];
  float4* dst = (float4*)(out + (size_t)r0 * W_);
  for (int i = tid; i < CHUNKS_; i += 256) {
    int row_local = i / RCH_;
    int j = i - row_local * RCH_;
    int base = row_local * W_;
    float res[4];
#pragma unroll
    for (int k = 0; k < 4; ++k) {
      int pl = swl_s[j * 4 + k];
      int s = pl & 0xFFFF;
      int r = pl >> 16;
      float dv = (r == 0) ? d0 : (r == 1) ? d1 : (r == 2) ? d2 : d3;
      res[k] = tile[base + s] + dv;
    }
    dst[i] = make_float4(res[0], res[1], res[2], res[3]);
  }
}

extern "C" void kernel_launch(void* const* d_in, const int* in_sizes, int n_in,
                              void* d_out, int out_size, void* d_ws, size_t ws_size,
                              hipStream_t stream) {
  const float* img  = (const float*)d_in[0];   // image_feature (B,C,H,W) fp32
  const float* tf   = (const float*)d_in[1];   // text_feat (NREG,B,HID) fp32
  const int*   mask = (const int*)d_in[2];     // text_mask (B,1,H*DS,W*DS) int32
  // d_in[3] = Wq (unused), d_in[4] = Wk (unused)
  const float* Wv   = (const float*)d_in[5];   // (NREG,HID,HID) fp32
  const float* Wo   = (const float*)d_in[6];   // (NREG,HID,C) fp32
  float* delta = (float*)d_ws;
  float* tmp   = (float*)((char*)d_ws + 32768);
  int*   swl   = (int*)((char*)d_ws + 65536);
  float* out   = (float*)d_out;

  hipMemsetAsync(d_ws, 0, 65536, stream);  // zero delta + tmp (atomic accumulators)
  prep1_kernel<<<36, 256, 0, stream>>>(tf, Wv, mask, tmp, swl);
  prep2_kernel<<<32, 256, 0, stream>>>(tmp, Wo, delta);
  apply_kernel<<<(B_ * C_ * H_) / ROWS_, 256, 0, stream>>>(img, delta, swl, out);
}

// Round 3
// 242.141 us; speedup vs baseline: 1.0573x; 1.0573x over previous
//
#include <hip/hip_runtime.h>

#define B_ 4
#define C_ 512
#define H_ 64
#define W_ 208
#define HID_ 512
#define NREG_ 4
#define DS_ 16

// ws layout: delta [B*NREG*C_] fp32 @0 (32KB) | tmp [B*NREG*HID_] fp32 @32KB | swl [B*W] int @64KB

// Blocks 0..255: partial tmp[b,r,d] += sum_{h in 16-chunk} tf[r,b,h]*Wv[r,h,d]
//   grid decomp: r = blk>>6, h-chunk64 = (blk>>3)&7, d-chunk64 = blk&7
// Blocks 256..259: parallel stable counting sort of column labels for b = blk-256
__global__ __launch_bounds__(256) void prepA_kernel(
    const float* __restrict__ tf, const float* __restrict__ Wv,
    const int* __restrict__ mask, float* __restrict__ tmp, int* __restrict__ swl) {
  int blk = blockIdx.x, tid = threadIdx.x;
  if (blk < 256) {
    int r = blk >> 6;
    int h0 = ((blk >> 3) & 7) * 64;
    int d0 = (blk & 7) * 64;
    int g = tid >> 6, dd = tid & 63;
    __shared__ float tf_s[B_][64];
    __shared__ float red[4][B_][64];
    tf_s[g][dd] = tf[(r * B_ + g) * HID_ + h0 + dd];  // g as b, dd as hh
    __syncthreads();
    float acc[B_] = {};
    for (int hh = g * 16; hh < g * 16 + 16; ++hh) {
      float w = Wv[(size_t)(r * HID_ + h0 + hh) * HID_ + d0 + dd];
#pragma unroll
      for (int b = 0; b < B_; ++b) acc[b] += tf_s[b][hh] * w;
    }
#pragma unroll
    for (int b = 0; b < B_; ++b) red[g][b][dd] = acc[b];
    __syncthreads();
    {  // g now indexes b
      float s = red[0][g][dd] + red[1][g][dd] + red[2][g][dd] + red[3][g][dd];
      atomicAdd(&tmp[(g * NREG_ + r) * HID_ + d0 + dd], s);
    }
  } else {
    int b = blk - 256;
    const size_t mb = (size_t)b * (H_ * DS_) * (W_ * DS_);
    int w = tid;
    int l = (w < W_) ? (mask[mb + (size_t)w * DS_] - 1) : -1;
    int wave = tid >> 6, lane = tid & 63;
    unsigned long long bal[NREG_];
    __shared__ int wcnt[4][NREG_];
#pragma unroll
    for (int r = 0; r < NREG_; ++r) bal[r] = __ballot(l == r);
    if (lane < NREG_) wcnt[wave][lane] = __popcll(bal[lane]);
    __syncthreads();
    if (w < W_) {
      int pos = 0;
#pragma unroll
      for (int q = 0; q < NREG_; ++q) {
        int tot = wcnt[0][q] + wcnt[1][q] + wcnt[2][q] + wcnt[3][q];
        if (q < l) pos += tot;
      }
#pragma unroll
      for (int v = 0; v < 4; ++v)
        if (v < wave) pos += wcnt[v][l];
      pos += __popcll(bal[l] & ((1ull << lane) - 1ull));
      swl[b * W_ + pos] = w | (l << 16);
    }
  }
}

// delta[b,r,c] += sum_{d in 16-chunk} tmp[b,r,d]*Wo[r,d,c]; same decomp as prepA
__global__ __launch_bounds__(256) void prepB_kernel(
    const float* __restrict__ tmp, const float* __restrict__ Wo,
    float* __restrict__ delta) {
  int blk = blockIdx.x, tid = threadIdx.x;
  int r = blk >> 6;
  int d0 = ((blk >> 3) & 7) * 64;
  int c0 = (blk & 7) * 64;
  int g = tid >> 6, cc = tid & 63;
  __shared__ float tmp_s[B_][64];
  __shared__ float red[4][B_][64];
  tmp_s[g][cc] = tmp[(g * NREG_ + r) * HID_ + d0 + cc];  // g as b, cc as dd
  __syncthreads();
  float acc[B_] = {};
  for (int dd = g * 16; dd < g * 16 + 16; ++dd) {
    float w = Wo[(size_t)(r * HID_ + d0 + dd) * C_ + c0 + cc];
#pragma unroll
    for (int b = 0; b < B_; ++b) acc[b] += tmp_s[b][dd] * w;
  }
#pragma unroll
  for (int b = 0; b < B_; ++b) red[g][b][cc] = acc[b];
  __syncthreads();
  {  // g now indexes b
    float s = red[0][g][cc] + red[1][g][cc] + red[2][g][cc] + red[3][g][cc];
    atomicAdd(&delta[(g * NREG_ + r) * C_ + c0 + cc], s);
  }
}

// Each block: 16 contiguous (b,c,h)-rows (constant b,c). Stage rows in LDS
// (float4 vectorized), gather-permute columns via LDS, add delta, store float4.
// ROWS_=16: LDS ~14.2KB -> 8 blocks/CU (wave-limited, 100% occupancy target).
#define ROWS_ 16
#define RCH_ (W_ / 4)              // 52 float4 chunks per row
#define CHUNKS_ (ROWS_ * RCH_)     // 832 per block
__global__ __launch_bounds__(256) void apply_kernel(
    const float* __restrict__ img, const float* __restrict__ delta,
    const int* __restrict__ swl, float* __restrict__ out) {
  int r0 = blockIdx.x * ROWS_;
  int b = r0 >> 15;                // / (C_*H_)
  int c = (r0 >> 6) & (C_ - 1);    // / H_ mod C_
  int tid = threadIdx.x;
  __shared__ float tile[ROWS_ * W_];
  __shared__ int swl_s[W_];
  __shared__ float dsel_s[NREG_];
  const float4* src = (const float4*)(img + (size_t)r0 * W_);
  float4* tile4 = (float4*)tile;
  for (int i = tid; i < CHUNKS_; i += 256) tile4[i] = src[i];
  if (tid < W_) swl_s[tid] = swl[b * W_ + tid];
  if (tid < NREG_) dsel_s[tid] = delta[(b * NREG_ + tid) * C_ + c];
  __syncthreads();
  float d0 = dsel_s[0], d1 = dsel_s[1], d2 = dsel_s[2], d3 = dsel_s[3];
  float4* dst = (float4*)(out + (size_t)r0 * W_);
  for (int i = tid; i < CHUNKS_; i += 256) {
    int row_local = i / RCH_;
    int j = i - row_local * RCH_;
    int base = row_local * W_;
    float res[4];
#pragma unroll
    for (int k = 0; k < 4; ++k) {
      int pl = swl_s[j * 4 + k];
      int s = pl & 0xFFFF;
      int r = pl >> 16;
      float dv = (r == 0) ? d0 : (r == 1) ? d1 : (r == 2) ? d2 : d3;
      res[k] = tile[base + s] + dv;
    }
    dst[i] = make_float4(res[0], res[1], res[2], res[3]);
  }
}

extern "C" void kernel_launch(void* const* d_in, const int* in_sizes, int n_in,
                              void* d_out, int out_size, void* d_ws, size_t ws_size,
                              hipStream_t stream) {
  const float* img  = (const float*)d_in[0];   // image_feature (B,C,H,W) fp32
  const float* tf   = (const float*)d_in[1];   // text_feat (NREG,B,HID) fp32
  const int*   mask = (const int*)d_in[2];     // text_mask (B,1,H*DS,W*DS) int32
  // d_in[3] = Wq (unused), d_in[4] = Wk (unused)
  const float* Wv   = (const float*)d_in[5];   // (NREG,HID,HID) fp32
  const float* Wo   = (const float*)d_in[6];   // (NREG,HID,C) fp32
  float* delta = (float*)d_ws;
  float* tmp   = (float*)((char*)d_ws + 32768);
  int*   swl   = (int*)((char*)d_ws + 65536);
  float* out   = (float*)d_out;

  hipMemsetAsync(d_ws, 0, 65536, stream);  // zero delta + tmp (atomic accumulators)
  prepA_kernel<<<260, 256, 0, stream>>>(tf, Wv, mask, tmp, swl);
  prepB_kernel<<<256, 256, 0, stream>>>(tmp, Wo, delta);
  apply_kernel<<<(B_ * C_ * H_) / ROWS_, 256, 0, stream>>>(img, delta, swl, out);
}